// Round 3
// baseline (1006.639 us; speedup 1.0000x reference)
//
#include <hip/hip_runtime.h>
#include <hip/hip_bf16.h>

typedef unsigned short ushort_t;
typedef __bf16 bf16x8 __attribute__((ext_vector_type(8)));
typedef float f32x4 __attribute__((ext_vector_type(4)));
typedef float f32x8 __attribute__((ext_vector_type(8)));

#define NTOK 1032
#define NROWS 8256       // B*N = 8*1032
#define DIMC 1024
#define QKV_ELEMS 8454144  // 8*16*1032*64 elements per tensor (Q,K,V)

__device__ __forceinline__ float bf2f(ushort_t u) {
    union { unsigned int i; float f; } v; v.i = ((unsigned int)u) << 16; return v.f;
}
__device__ __forceinline__ ushort_t f2bf(float f) {
    union { float f; unsigned int i; } v; v.f = f;
    unsigned int r = v.i + 0x7fffu + ((v.i >> 16) & 1u);
    return (ushort_t)(r >> 16);
}
// load 8 fp32, convert to bf16x8 (RNE via hardware fptrunc)
__device__ __forceinline__ bf16x8 cvt8(const float* p) {
    const float4 a = *(const float4*)p;
    const float4 b = *(const float4*)(p + 4);
    bf16x8 r;
    r[0] = (__bf16)a.x; r[1] = (__bf16)a.y; r[2] = (__bf16)a.z; r[3] = (__bf16)a.w;
    r[4] = (__bf16)b.x; r[5] = (__bf16)b.y; r[6] = (__bf16)b.z; r[7] = (__bf16)b.w;
    return r;
}

// ---------------------------------------------------------------------------
// GEMM: C[m,o] = sum_k A[m,k] * W[o,k]
// MODE 0: A = hidden (fp32 [8256,1024]), W = qkv_w (fp32 [3072,1024])
//         -> scatter epilogue QKV bf16 [part][b*16+h][n][d]
// MODE 1: A = AO (bf16 [8256,1024]),    W = out_w (fp32 [1024,1024])
//         -> store fp32 row-major to Out
// 128x128 tile, 256 threads = 4 waves (2x2 of 64x64), K-step 32, bf16 MFMA.
// fp32 operands are converted to bf16 during LDS staging (no fp32 MFMA on CDNA4).
// ---------------------------------------------------------------------------
template<int MODE>
__global__ __launch_bounds__(256) void gemm_kernel(
    const void* __restrict__ Ap, const float* __restrict__ Wp,
    ushort_t* __restrict__ QKV, float* __restrict__ Out)
{
    __shared__ __align__(16) ushort_t As[128 * 32];
    __shared__ __align__(16) ushort_t Bs[128 * 32];
    const int tid  = threadIdx.x;
    const int wave = tid >> 6, lane = tid & 63;
    const int m0 = blockIdx.y * 128;
    const int n0 = blockIdx.x * 128;

    f32x4 acc[4][4] = {};

    // staging: slot s in [0,512): row = s>>2, 8-elem chunk = s&3
    const int s0 = tid, s1 = tid + 256;
    int ar0 = m0 + (s0 >> 2); if (ar0 > NROWS - 1) ar0 = NROWS - 1;
    int ar1 = m0 + (s1 >> 2); if (ar1 > NROWS - 1) ar1 = NROWS - 1;
    const int br0 = n0 + (s0 >> 2);
    const int br1 = n0 + (s1 >> 2);
    const int kc0 = (s0 & 3) * 8, kc1 = (s1 & 3) * 8;

    const float*    gaf0 = (const float*)Ap    + (long)ar0 * DIMC + kc0;
    const float*    gaf1 = (const float*)Ap    + (long)ar1 * DIMC + kc1;
    const ushort_t* gab0 = (const ushort_t*)Ap + (long)ar0 * DIMC + kc0;
    const ushort_t* gab1 = (const ushort_t*)Ap + (long)ar1 * DIMC + kc1;
    const float*    gw0  = Wp + (long)br0 * DIMC + kc0;
    const float*    gw1  = Wp + (long)br1 * DIMC + kc1;
    ushort_t* la0 = &As[s0 * 8];
    ushort_t* la1 = &As[s1 * 8];
    ushort_t* lb0 = &Bs[s0 * 8];
    ushort_t* lb1 = &Bs[s1 * 8];

    const int wm = (wave >> 1) * 64, wn = (wave & 1) * 64;
    const int fr = lane & 15, fk = (lane >> 4) * 8;

    for (int k0 = 0; k0 < DIMC; k0 += 32) {
        bf16x8 ra0, ra1;
        if (MODE == 0) {
            ra0 = cvt8(gaf0 + k0);
            ra1 = cvt8(gaf1 + k0);
        } else {
            ra0 = *(const bf16x8*)(gab0 + k0);
            ra1 = *(const bf16x8*)(gab1 + k0);
        }
        const bf16x8 rb0 = cvt8(gw0 + k0);
        const bf16x8 rb1 = cvt8(gw1 + k0);
        *(bf16x8*)la0 = ra0;
        *(bf16x8*)la1 = ra1;
        *(bf16x8*)lb0 = rb0;
        *(bf16x8*)lb1 = rb1;
        __syncthreads();

        bf16x8 af[4], bfr[4];
        #pragma unroll
        for (int mi = 0; mi < 4; ++mi)
            af[mi] = *(const bf16x8*)&As[(wm + mi * 16 + fr) * 32 + fk];
        #pragma unroll
        for (int ni = 0; ni < 4; ++ni)
            bfr[ni] = *(const bf16x8*)&Bs[(wn + ni * 16 + fr) * 32 + fk];
        #pragma unroll
        for (int mi = 0; mi < 4; ++mi)
            #pragma unroll
            for (int ni = 0; ni < 4; ++ni)
                acc[mi][ni] = __builtin_amdgcn_mfma_f32_16x16x32_bf16(
                    af[mi], bfr[ni], acc[mi][ni], 0, 0, 0);
        __syncthreads();
    }

    // epilogue: C/D layout col = lane&15, row = (lane>>4)*4 + reg  [m89/m91]
    const int col = lane & 15, rb = (lane >> 4) * 4;
    #pragma unroll
    for (int mi = 0; mi < 4; ++mi) {
        #pragma unroll
        for (int ni = 0; ni < 4; ++ni) {
            const int o = n0 + wn + ni * 16 + col;
            #pragma unroll
            for (int reg = 0; reg < 4; ++reg) {
                const int m = m0 + wm + mi * 16 + rb + reg;
                if (m < NROWS) {
                    const float v = acc[mi][ni][reg];
                    if (MODE == 0) {
                        const int part = o >> 10, rem = o & 1023;
                        const int h = rem >> 6, d = rem & 63;
                        const int b = m / NTOK, n = m - b * NTOK;
                        const long dst = ((long)(b * 16 + h) * NTOK + n) * 64 + d;
                        QKV[(long)part * QKV_ELEMS + dst] = f2bf(v);
                    } else {
                        Out[(long)m * DIMC + o] = v;
                    }
                }
            }
        }
    }
}

// ---------------------------------------------------------------------------
// RMSNorm (per 64-dim head vector) + RoPE, in-place on bf16 Q / K.
// One wave per (tensor, b, h, n); lane = dim. Tables/weights are fp32.
// ---------------------------------------------------------------------------
__global__ __launch_bounds__(256) void rope_kernel(
    ushort_t* __restrict__ Qb, ushort_t* __restrict__ Kb,
    const float* __restrict__ cosb, const float* __restrict__ sinb,
    const float* __restrict__ wq, const float* __restrict__ wk)
{
    const int wave = threadIdx.x >> 6, lane = threadIdx.x & 63;
    const int t = blockIdx.x * 4 + wave;        // [0, 2*132096)
    const int tensor = (t >= 132096) ? 1 : 0;
    const int r = t - tensor * 132096;          // bh*1032 + n
    const int n = r % NTOK;
    ushort_t* base = (tensor ? Kb : Qb) + (long)r * 64;

    const float x = bf2f(base[lane]);
    float ss = x * x;
    #pragma unroll
    for (int off = 32; off; off >>= 1) ss += __shfl_xor(ss, off);
    const float rms = rsqrtf(ss * (1.0f / 64.0f) + 1e-6f);
    const float w = (tensor ? wk : wq)[lane];
    const float xn = x * rms * w;
    const float partner = __shfl_xor(xn, 32);
    const float rot = (lane < 32) ? -partner : partner; // rotate-half
    const float c = cosb[n * 64 + lane];
    const float s = sinb[n * 64 + lane];
    base[lane] = f2bf(xn * c + rot * s);
}

// ---------------------------------------------------------------------------
// Attention: one wave per (b,h,q). Patch queries: key set = 8 specials +
// clamped 7x7 box = 57 keys (single 64-lane batch). Special queries: all 1032.
// Online softmax; scores lane=key, PV lane=dim via 64-float LDS bounce.
// Output -> AO [b*1032+n, h*64+d] bf16.
// ---------------------------------------------------------------------------
__global__ __launch_bounds__(256) void attn_kernel(
    const ushort_t* __restrict__ Qb, const ushort_t* __restrict__ Kb,
    const ushort_t* __restrict__ Vb, ushort_t* __restrict__ AO)
{
    __shared__ __align__(16) float q_lds[4][64];
    __shared__ float p_lds[4][64];
    const int wave = threadIdx.x >> 6, lane = threadIdx.x & 63;
    const int task = blockIdx.x * 4 + wave;  // bh*1032 + q
    const int q = task % NTOK;
    const int bh = task / NTOK;
    const ushort_t* Qrow = Qb + ((long)bh * NTOK + q) * 64;
    const ushort_t* K = Kb + (long)bh * NTOK * 64;
    const ushort_t* V = Vb + (long)bh * NTOK * 64;

    q_lds[wave][lane] = bf2f(Qrow[lane]);
    __syncthreads();

    const bool special = (q < 8);
    int nkeys, r0 = 0, c0 = 0, qr = 0, qc = 0;
    if (special) { nkeys = NTOK; }
    else {
        const int p = q - 8; qr = p >> 5; qc = p & 31;
        r0 = qr - 3; if (r0 < 0) r0 = 0; if (r0 > 25) r0 = 25;
        c0 = qc - 3; if (c0 < 0) c0 = 0; if (c0 > 25) c0 = 25;
        nkeys = 57; // 8 specials + 7x7 box
    }

    float m_run = -1e30f, l_run = 0.f, o_acc = 0.f;
    for (int base = 0; base < nkeys; base += 64) {
        const int i = base + lane;
        float s = -1e30f;
        bool valid = false;
        int n = 0;
        if (i < nkeys) {
            if (special || i < 8) { n = i; valid = true; }
            else {
                const int j = i - 8;
                const int jr = (j * 37) >> 8;   // j/7 for j<=48
                const int jc = j - jr * 7;
                const int kr = r0 + jr, kc = c0 + jc;
                n = 8 + kr * 32 + kc;
                const int dr = kr - qr, dc = kc - qc;
                valid = (dr >= -3) & (dr <= 3) & (dc >= -3) & (dc <= 3);
            }
        }
        if (valid) {
            const bf16x8* krow = (const bf16x8*)(K + (long)n * 64);
            float acc = 0.f;
            #pragma unroll
            for (int c = 0; c < 8; ++c) {
                const f32x8 kf = __builtin_convertvector(krow[c], f32x8);
                const f32x8 qf = *(const f32x8*)&q_lds[wave][c * 8];
                acc += kf[0]*qf[0] + kf[1]*qf[1] + kf[2]*qf[2] + kf[3]*qf[3]
                     + kf[4]*qf[4] + kf[5]*qf[5] + kf[6]*qf[6] + kf[7]*qf[7];
            }
            s = acc * 0.125f;
        }
        float bm = s;
        #pragma unroll
        for (int off = 32; off; off >>= 1) bm = fmaxf(bm, __shfl_xor(bm, off));
        const float m_new = fmaxf(m_run, bm);
        const float pv = valid ? __expf(s - m_new) : 0.f;
        p_lds[wave][lane] = pv;
        float bs = pv;
        #pragma unroll
        for (int off = 32; off; off >>= 1) bs += __shfl_xor(bs, off);
        const float alpha = __expf(m_run - m_new);
        l_run = l_run * alpha + bs;
        o_acc *= alpha;

        int lim = nkeys - base; if (lim > 64) lim = 64;
        for (int jj = 0; jj < lim; ++jj) {
            const float pj = p_lds[wave][jj];   // wave-uniform
            if (pj != 0.f) {
                const int i2 = base + jj;
                int n2;
                if (special || i2 < 8) n2 = i2;
                else {
                    const int j = i2 - 8;
                    const int jr = (j * 37) >> 8;
                    const int jc = j - jr * 7;
                    n2 = 8 + (r0 + jr) * 32 + (c0 + jc);
                }
                o_acc += pj * bf2f(V[(long)n2 * 64 + lane]);
            }
        }
        m_run = m_new;
    }

    const float outv = o_acc / l_run;
    const int b = bh >> 4, h = bh & 15;
    AO[((long)(b * NTOK + q)) * DIMC + h * 64 + lane] = f2bf(outv);
}

extern "C" void kernel_launch(void* const* d_in, const int* in_sizes, int n_in,
                              void* d_out, int out_size, void* d_ws, size_t ws_size,
                              hipStream_t stream) {
    const float* X    = (const float*)d_in[0];   // [8,1032,1024] fp32
    const float* fc   = (const float*)d_in[1];   // [1032,64] fp32
    const float* fs   = (const float*)d_in[2];
    const float* qkvw = (const float*)d_in[3];   // [3072,1024] fp32
    const float* outw = (const float*)d_in[4];   // [1024,1024] fp32
    const float* nqw  = (const float*)d_in[5];   // [64] fp32
    const float* nkw  = (const float*)d_in[6];

    ushort_t* Qb = (ushort_t*)d_ws;          // 16,908,288 B each, 67.6 MB total
    ushort_t* Kb = Qb + QKV_ELEMS;
    ushort_t* Vb = Kb + QKV_ELEMS;
    ushort_t* AO = Vb + QKV_ELEMS;
    float* Out = (float*)d_out;

    // 1) QKV projection (fp32 in, bf16 MFMA core) + scatter to head-major bf16
    gemm_kernel<0><<<dim3(24, 65), 256, 0, stream>>>(X, qkvw, Qb, nullptr);
    // 2) RMSNorm + RoPE in-place on Q,K
    rope_kernel<<<66048, 256, 0, stream>>>(Qb, Kb, fc, fs, nqw, nkw);
    // 3) masked attention -> AO (bf16)
    attn_kernel<<<33024, 256, 0, stream>>>(Qb, Kb, Vb, AO);
    // 4) output projection -> fp32 d_out
    gemm_kernel<1><<<dim3(8, 65), 256, 0, stream>>>(AO, outw, nullptr, Out);
}

// Round 5
// 445.402 us; speedup vs baseline: 2.2601x; 2.2601x over previous
//
#include <hip/hip_runtime.h>
#include <hip/hip_bf16.h>

typedef unsigned short ushort_t;
typedef __bf16 bf16x8 __attribute__((ext_vector_type(8)));
typedef float f32x4 __attribute__((ext_vector_type(4)));

#define NTOK 1032
#define NROWS 8256       // B*N = 8*1032
#define DIMC 1024
#define QKV_ELEMS 8454144  // 8*16*1032*64 elements per tensor

__device__ __forceinline__ float bf2f(ushort_t u) {
    union { unsigned int i; float f; } v; v.i = ((unsigned int)u) << 16; return v.f;
}
__device__ __forceinline__ ushort_t f2bf(float f) {
    union { float f; unsigned int i; } v; v.f = f;
    unsigned int r = v.i + 0x7fffu + ((v.i >> 16) & 1u);
    return (ushort_t)(r >> 16);
}
__device__ __forceinline__ bf16x8 cvt8(const float* p) {
    const float4 a = *(const float4*)p;
    const float4 b = *(const float4*)(p + 4);
    bf16x8 r;
    r[0] = (__bf16)a.x; r[1] = (__bf16)a.y; r[2] = (__bf16)a.z; r[3] = (__bf16)a.w;
    r[4] = (__bf16)b.x; r[5] = (__bf16)b.y; r[6] = (__bf16)b.z; r[7] = (__bf16)b.w;
    return r;
}

// ---------------------------------------------------------------------------
// GEMM (unchanged core). MODE 0: QKV proj, scatter Q/K token-major, V DIM-MAJOR
// (Vt[bh][d][n]) so attention PV B-fragments are contiguous. MODE 1: out proj.
// ---------------------------------------------------------------------------
template<int MODE>
__global__ __launch_bounds__(256) void gemm_kernel(
    const void* __restrict__ Ap, const float* __restrict__ Wp,
    ushort_t* __restrict__ QKV, float* __restrict__ Out)
{
    __shared__ __align__(16) ushort_t As[128 * 32];
    __shared__ __align__(16) ushort_t Bs[128 * 32];
    const int tid  = threadIdx.x;
    const int wave = tid >> 6, lane = tid & 63;
    const int m0 = blockIdx.y * 128;
    const int n0 = blockIdx.x * 128;

    f32x4 acc[4][4] = {};

    const int s0 = tid, s1 = tid + 256;
    int ar0 = m0 + (s0 >> 2); if (ar0 > NROWS - 1) ar0 = NROWS - 1;
    int ar1 = m0 + (s1 >> 2); if (ar1 > NROWS - 1) ar1 = NROWS - 1;
    const int br0 = n0 + (s0 >> 2);
    const int br1 = n0 + (s1 >> 2);
    const int kc0 = (s0 & 3) * 8, kc1 = (s1 & 3) * 8;

    const float*    gaf0 = (const float*)Ap    + (long)ar0 * DIMC + kc0;
    const float*    gaf1 = (const float*)Ap    + (long)ar1 * DIMC + kc1;
    const ushort_t* gab0 = (const ushort_t*)Ap + (long)ar0 * DIMC + kc0;
    const ushort_t* gab1 = (const ushort_t*)Ap + (long)ar1 * DIMC + kc1;
    const float*    gw0  = Wp + (long)br0 * DIMC + kc0;
    const float*    gw1  = Wp + (long)br1 * DIMC + kc1;
    ushort_t* la0 = &As[s0 * 8];
    ushort_t* la1 = &As[s1 * 8];
    ushort_t* lb0 = &Bs[s0 * 8];
    ushort_t* lb1 = &Bs[s1 * 8];

    const int wm = (wave >> 1) * 64, wn = (wave & 1) * 64;
    const int fr = lane & 15, fk = (lane >> 4) * 8;

    for (int k0 = 0; k0 < DIMC; k0 += 32) {
        bf16x8 ra0, ra1;
        if (MODE == 0) {
            ra0 = cvt8(gaf0 + k0);
            ra1 = cvt8(gaf1 + k0);
        } else {
            ra0 = *(const bf16x8*)(gab0 + k0);
            ra1 = *(const bf16x8*)(gab1 + k0);
        }
        const bf16x8 rb0 = cvt8(gw0 + k0);
        const bf16x8 rb1 = cvt8(gw1 + k0);
        *(bf16x8*)la0 = ra0;
        *(bf16x8*)la1 = ra1;
        *(bf16x8*)lb0 = rb0;
        *(bf16x8*)lb1 = rb1;
        __syncthreads();

        bf16x8 af[4], bfr[4];
        #pragma unroll
        for (int mi = 0; mi < 4; ++mi)
            af[mi] = *(const bf16x8*)&As[(wm + mi * 16 + fr) * 32 + fk];
        #pragma unroll
        for (int ni = 0; ni < 4; ++ni)
            bfr[ni] = *(const bf16x8*)&Bs[(wn + ni * 16 + fr) * 32 + fk];
        #pragma unroll
        for (int mi = 0; mi < 4; ++mi)
            #pragma unroll
            for (int ni = 0; ni < 4; ++ni)
                acc[mi][ni] = __builtin_amdgcn_mfma_f32_16x16x32_bf16(
                    af[mi], bfr[ni], acc[mi][ni], 0, 0, 0);
        __syncthreads();
    }

    const int col = lane & 15, rb = (lane >> 4) * 4;
    #pragma unroll
    for (int mi = 0; mi < 4; ++mi) {
        #pragma unroll
        for (int ni = 0; ni < 4; ++ni) {
            const int o = n0 + wn + ni * 16 + col;
            #pragma unroll
            for (int reg = 0; reg < 4; ++reg) {
                const int m = m0 + wm + mi * 16 + rb + reg;
                if (m < NROWS) {
                    const float v = acc[mi][ni][reg];
                    if (MODE == 0) {
                        const int part = o >> 10, rem = o & 1023;
                        const int h = rem >> 6, d = rem & 63;
                        const int b = m / NTOK, n = m - b * NTOK;
                        const int bh = b * 16 + h;
                        long dst;
                        if (part == 2) dst = 2L * QKV_ELEMS + ((long)bh * 64 + d) * NTOK + n;
                        else dst = (long)part * QKV_ELEMS + ((long)bh * NTOK + n) * 64 + d;
                        QKV[dst] = f2bf(v);
                    } else {
                        Out[(long)m * DIMC + o] = v;
                    }
                }
            }
        }
    }
}

// ---------------------------------------------------------------------------
// RMSNorm + RoPE in-place on bf16 Q / K (token-major). Unchanged.
// ---------------------------------------------------------------------------
__global__ __launch_bounds__(256) void rope_kernel(
    ushort_t* __restrict__ Qb, ushort_t* __restrict__ Kb,
    const float* __restrict__ cosb, const float* __restrict__ sinb,
    const float* __restrict__ wq, const float* __restrict__ wk)
{
    const int wave = threadIdx.x >> 6, lane = threadIdx.x & 63;
    const int t = blockIdx.x * 4 + wave;
    const int tensor = (t >= 132096) ? 1 : 0;
    const int r = t - tensor * 132096;
    const int n = r % NTOK;
    ushort_t* base = (tensor ? Kb : Qb) + (long)r * 64;

    const float x = bf2f(base[lane]);
    float ss = x * x;
    #pragma unroll
    for (int off = 32; off; off >>= 1) ss += __shfl_xor(ss, off);
    const float rms = rsqrtf(ss * (1.0f / 64.0f) + 1e-6f);
    const float w = (tensor ? wk : wq)[lane];
    const float xn = x * rms * w;
    const float partner = __shfl_xor(xn, 32);
    const float rot = (lane < 32) ? -partner : partner;
    const float c = cosb[n * 64 + lane];
    const float s = sinb[n * 64 + lane];
    base[lane] = f2bf(xn * c + rot * s);
}

// ---------------------------------------------------------------------------
// Patch attention: one WG (4 waves) per (bh, qrow). Keys = 8 specials +
// clamped rows qr+-3 (<=232, padded to 256). MFMA QK^T -> mask+exp (max-free:
// |q|=|k|=8 => |s|<=8) -> P in LDS -> MFMA PV with Vt. Row sums via shfl +
// LDS atomicAdd; divide in epilogue.
// LDS strides 72 / 280 keep fragment reads at <=2-way bank aliasing.
// ---------------------------------------------------------------------------
__global__ __launch_bounds__(256) void attn_patch_kernel(
    const ushort_t* __restrict__ Qb, const ushort_t* __restrict__ Kb,
    const ushort_t* __restrict__ Vt, ushort_t* __restrict__ AO)
{
    __shared__ __align__(16) ushort_t Q_s[32 * 72];    //  4608 B
    __shared__ __align__(16) ushort_t KV_s[256 * 72];  // 36864 B (K, then Vt)
    __shared__ __align__(16) ushort_t P_s[32 * 280];   // 17920 B
    __shared__ float l_s[32];

    const int tid = threadIdx.x;
    const int wave = tid >> 6, lane = tid & 63;
    const int m_ = lane & 15, quad = lane >> 4;
    const int bh = blockIdx.x >> 5, qr = blockIdx.x & 31;
    const int b = bh >> 4, h = bh & 15;

    int r0 = qr - 3; if (r0 < 0) r0 = 0;
    int r1 = qr + 3; if (r1 > 31) r1 = 31;
    const int nrows = r1 - r0 + 1;            // 4..7
    const int limit = 8 + nrows * 32;         // 136..232

    const ushort_t* Qg  = Qb + ((long)bh * NTOK + 8 + qr * 32) * 64;
    const ushort_t* Kg  = Kb + (long)bh * NTOK * 64;
    const ushort_t* Vtg = Vt + (long)bh * 64 * NTOK;

    if (tid < 32) l_s[tid] = 0.f;
    // stage Q: 32 rows x 64 -> [32][72]
    {
        const int row = tid >> 3, c8 = (tid & 7) * 8;
        *(bf16x8*)&Q_s[row * 72 + c8] = *(const bf16x8*)(Qg + row * 64 + c8);
    }
    // stage K: slots [0,limit) -> [slot][72]
    for (int c = tid; c < limit * 8; c += 256) {
        const int slot = c >> 3, c8 = (c & 7) * 8;
        const int tok = slot + (slot >= 8 ? r0 * 32 : 0);
        *(bf16x8*)&KV_s[slot * 72 + c8] = *(const bf16x8*)(Kg + (long)tok * 64 + c8);
    }
    __syncthreads();

    // ---- S = QK^T, mask, exp, P->LDS, row sums ----
    const int nb = wave * 64;
    {
        bf16x8 af[2][2], bfr[4][2];
        #pragma unroll
        for (int mt = 0; mt < 2; ++mt)
            #pragma unroll
            for (int ks = 0; ks < 2; ++ks)
                af[mt][ks] = *(const bf16x8*)&Q_s[(mt * 16 + m_) * 72 + ks * 32 + quad * 8];
        #pragma unroll
        for (int nt = 0; nt < 4; ++nt)
            #pragma unroll
            for (int ks = 0; ks < 2; ++ks)
                bfr[nt][ks] = *(const bf16x8*)&KV_s[(nb + nt * 16 + m_) * 72 + ks * 32 + quad * 8];

        f32x4 sacc[2][4] = {};
        #pragma unroll
        for (int mt = 0; mt < 2; ++mt)
            #pragma unroll
            for (int nt = 0; nt < 4; ++nt) {
                sacc[mt][nt] = __builtin_amdgcn_mfma_f32_16x16x32_bf16(
                    af[mt][0], bfr[nt][0], sacc[mt][nt], 0, 0, 0);
                sacc[mt][nt] = __builtin_amdgcn_mfma_f32_16x16x32_bf16(
                    af[mt][1], bfr[nt][1], sacc[mt][nt], 0, 0, 0);
            }

        #pragma unroll
        for (int mt = 0; mt < 2; ++mt)
            #pragma unroll
            for (int nt = 0; nt < 4; ++nt) {
                const int slot = nb + nt * 16 + m_;
                const int kc = (slot - 8) & 31;
                #pragma unroll
                for (int reg = 0; reg < 4; ++reg) {
                    const int qm = mt * 16 + quad * 4 + reg;   // query col within row
                    const bool val = (slot < 8) ||
                        ((slot < limit) && ((unsigned)(kc - qm + 3) <= 6u));
                    const float s = sacc[mt][nt][reg];
                    const float p = val ? __expf(s * 0.125f) : 0.f;
                    P_s[qm * 280 + slot] = f2bf(p);
                    float rs = p;
                    #pragma unroll
                    for (int off = 1; off < 16; off <<= 1) rs += __shfl_xor(rs, off);
                    if (m_ == 0) atomicAdd(&l_s[qm], rs);
                }
            }
    }
    __syncthreads();

    // ---- stage Vt chunk -> KV_s as [64][280] (zero pad cols) ----
    for (int c = tid; c < 2048; c += 256) {
        const int d = c >> 5, j = c & 31, slot0 = j * 8;
        bf16x8 v;
        if (slot0 >= limit) {
            #pragma unroll
            for (int e = 0; e < 8; ++e) v[e] = (__bf16)0.f;
        } else {
            const int tok0 = (j == 0) ? 0 : 8 + r0 * 32 + (slot0 - 8);
            v = *(const bf16x8*)(Vtg + (long)d * NTOK + tok0);
        }
        *(bf16x8*)&KV_s[d * 280 + slot0] = v;
    }
    __syncthreads();

    // ---- O = P * V ----
    {
        const int d0 = wave * 16;
        f32x4 oacc[2] = {};
        #pragma unroll
        for (int ks = 0; ks < 8; ++ks) {
            const bf16x8 bv = *(const bf16x8*)&KV_s[(d0 + m_) * 280 + ks * 32 + quad * 8];
            #pragma unroll
            for (int mt = 0; mt < 2; ++mt) {
                const bf16x8 ap = *(const bf16x8*)&P_s[(mt * 16 + m_) * 280 + ks * 32 + quad * 8];
                oacc[mt] = __builtin_amdgcn_mfma_f32_16x16x32_bf16(ap, bv, oacc[mt], 0, 0, 0);
            }
        }
        #pragma unroll
        for (int mt = 0; mt < 2; ++mt)
            #pragma unroll
            for (int reg = 0; reg < 4; ++reg) {
                const int qm = mt * 16 + quad * 4 + reg;
                const int tok = 8 + qr * 32 + qm;
                const float rl = l_s[qm];
                AO[((long)(b * NTOK + tok)) * DIMC + h * 64 + d0 + m_] =
                    f2bf(oacc[mt][reg] / rl);
            }
    }
}

// ---------------------------------------------------------------------------
// Special-token attention: one WG per bh; 8 queries (padded to 16) x all 1032
// keys in 5 chunks of 256. Same max-free softmax; O accumulates in regs.
// ---------------------------------------------------------------------------
__global__ __launch_bounds__(256) void attn_special_kernel(
    const ushort_t* __restrict__ Qb, const ushort_t* __restrict__ Kb,
    const ushort_t* __restrict__ Vt, ushort_t* __restrict__ AO)
{
    __shared__ __align__(16) ushort_t Q_s[16 * 72];
    __shared__ __align__(16) ushort_t KV_s[256 * 72];
    __shared__ __align__(16) ushort_t P_s[16 * 280];
    __shared__ float l_s[16];

    const int tid = threadIdx.x;
    const int wave = tid >> 6, lane = tid & 63;
    const int m_ = lane & 15, quad = lane >> 4;
    const int bh = blockIdx.x;
    const int b = bh >> 4, h = bh & 15;

    const ushort_t* Kg  = Kb + (long)bh * NTOK * 64;
    const ushort_t* Vtg = Vt + (long)bh * 64 * NTOK;

    if (tid < 16) l_s[tid] = 0.f;
    if (tid < 128) {
        const int row = tid >> 3, c8 = (tid & 7) * 8;
        bf16x8 v;
        if (row < 8) {
            v = *(const bf16x8*)(Qb + ((long)bh * NTOK + row) * 64 + c8);
        } else {
            #pragma unroll
            for (int e = 0; e < 8; ++e) v[e] = (__bf16)0.f;
        }
        *(bf16x8*)&Q_s[row * 72 + c8] = v;
    }

    const int d0 = wave * 16;
    const int nb = wave * 64;
    f32x4 oacc = {};

    for (int ch = 0; ch < 5; ++ch) {
        const int tok0 = ch * 256;
        const int limit = (NTOK - tok0 < 256) ? (NTOK - tok0) : 256;
        __syncthreads();   // previous PV done before overwriting KV_s
        for (int c = tid; c < limit * 8; c += 256) {
            const int slot = c >> 3, c8 = (c & 7) * 8;
            *(bf16x8*)&KV_s[slot * 72 + c8] =
                *(const bf16x8*)(Kg + (long)(tok0 + slot) * 64 + c8);
        }
        __syncthreads();

        // S phase
        {
            bf16x8 af[2], bfr[4][2];
            #pragma unroll
            for (int ks = 0; ks < 2; ++ks)
                af[ks] = *(const bf16x8*)&Q_s[m_ * 72 + ks * 32 + quad * 8];
            #pragma unroll
            for (int nt = 0; nt < 4; ++nt)
                #pragma unroll
                for (int ks = 0; ks < 2; ++ks)
                    bfr[nt][ks] = *(const bf16x8*)&KV_s[(nb + nt * 16 + m_) * 72 + ks * 32 + quad * 8];
            f32x4 sacc[4] = {};
            #pragma unroll
            for (int nt = 0; nt < 4; ++nt) {
                sacc[nt] = __builtin_amdgcn_mfma_f32_16x16x32_bf16(af[0], bfr[nt][0], sacc[nt], 0, 0, 0);
                sacc[nt] = __builtin_amdgcn_mfma_f32_16x16x32_bf16(af[1], bfr[nt][1], sacc[nt], 0, 0, 0);
            }
            #pragma unroll
            for (int nt = 0; nt < 4; ++nt) {
                const int slot = nb + nt * 16 + m_;
                const bool val = (slot < limit);
                #pragma unroll
                for (int reg = 0; reg < 4; ++reg) {
                    const int qm = quad * 4 + reg;
                    const float p = val ? __expf(sacc[nt][reg] * 0.125f) : 0.f;
                    P_s[qm * 280 + slot] = f2bf(p);
                    float rs = p;
                    #pragma unroll
                    for (int off = 1; off < 16; off <<= 1) rs += __shfl_xor(rs, off);
                    if (m_ == 0 && qm < 8) atomicAdd(&l_s[qm], rs);
                }
            }
        }
        __syncthreads();

        // stage Vt chunk [64][280]
        for (int c = tid; c < 2048; c += 256) {
            const int d = c >> 5, j = c & 31, slot0 = j * 8;
            bf16x8 v;
            if (slot0 >= limit) {
                #pragma unroll
                for (int e = 0; e < 8; ++e) v[e] = (__bf16)0.f;
            } else {
                v = *(const bf16x8*)(Vtg + (long)d * NTOK + tok0 + slot0);
            }
            *(bf16x8*)&KV_s[d * 280 + slot0] = v;
        }
        __syncthreads();

        // PV accumulate
        #pragma unroll
        for (int ks = 0; ks < 8; ++ks) {
            const bf16x8 bv = *(const bf16x8*)&KV_s[(d0 + m_) * 280 + ks * 32 + quad * 8];
            const bf16x8 ap = *(const bf16x8*)&P_s[m_ * 280 + ks * 32 + quad * 8];
            oacc = __builtin_amdgcn_mfma_f32_16x16x32_bf16(ap, bv, oacc, 0, 0, 0);
        }
    }
    __syncthreads();

    #pragma unroll
    for (int reg = 0; reg < 4; ++reg) {
        const int qm = quad * 4 + reg;
        if (qm < 8) {
            AO[((long)(b * NTOK + qm)) * DIMC + h * 64 + d0 + m_] =
                f2bf(oacc[reg] / l_s[qm]);
        }
    }
}

extern "C" void kernel_launch(void* const* d_in, const int* in_sizes, int n_in,
                              void* d_out, int out_size, void* d_ws, size_t ws_size,
                              hipStream_t stream) {
    const float* X    = (const float*)d_in[0];
    const float* fc   = (const float*)d_in[1];
    const float* fs   = (const float*)d_in[2];
    const float* qkvw = (const float*)d_in[3];
    const float* outw = (const float*)d_in[4];
    const float* nqw  = (const float*)d_in[5];
    const float* nkw  = (const float*)d_in[6];

    ushort_t* Qb = (ushort_t*)d_ws;
    ushort_t* Kb = Qb + QKV_ELEMS;
    ushort_t* Vt = Kb + QKV_ELEMS;   // dim-major: [bh][d][n]
    ushort_t* AO = Vt + QKV_ELEMS;
    float* Out = (float*)d_out;

    gemm_kernel<0><<<dim3(24, 65), 256, 0, stream>>>(X, qkvw, Qb, nullptr);
    rope_kernel<<<66048, 256, 0, stream>>>(Qb, Kb, fc, fs, nqw, nkw);
    attn_patch_kernel<<<4096, 256, 0, stream>>>(Qb, Kb, Vt, AO);
    attn_special_kernel<<<128, 256, 0, stream>>>(Qb, Kb, Vt, AO);
    gemm_kernel<1><<<dim3(8, 65), 256, 0, stream>>>(AO, outw, nullptr, Out);
}

// Round 6
// 413.239 us; speedup vs baseline: 2.4360x; 1.0778x over previous
//
#include <hip/hip_runtime.h>
#include <hip/hip_bf16.h>

typedef unsigned short ushort_t;
typedef __bf16 bf16x8 __attribute__((ext_vector_type(8)));
typedef float f32x4 __attribute__((ext_vector_type(4)));

#define NTOK 1032
#define NROWS 8256       // B*N = 8*1032
#define DIMC 1024
#define QKV_ELEMS 8454144  // 8*16*1032*64 elements per tensor
#define XE 8454144         // X elements (8256*1024)
#define QWE 3145728        // qkv_w elements (3072*1024)
#define OWE 1048576        // out_w elements (1024*1024)

__device__ __forceinline__ float bf2f(ushort_t u) {
    union { unsigned int i; float f; } v; v.i = ((unsigned int)u) << 16; return v.f;
}
__device__ __forceinline__ ushort_t f2bf(float f) {
    union { float f; unsigned int i; } v; v.f = f;
    unsigned int r = v.i + 0x7fffu + ((v.i >> 16) & 1u);
    return (ushort_t)(r >> 16);
}
__device__ __forceinline__ bf16x8 cvt8(const float* p) {
    const float4 a = *(const float4*)p;
    const float4 b = *(const float4*)(p + 4);
    bf16x8 r;
    r[0] = (__bf16)a.x; r[1] = (__bf16)a.y; r[2] = (__bf16)a.z; r[3] = (__bf16)a.w;
    r[4] = (__bf16)b.x; r[5] = (__bf16)b.y; r[6] = (__bf16)b.z; r[7] = (__bf16)b.w;
    return r;
}
__device__ __forceinline__ void load_lds16(const ushort_t* g, ushort_t* l) {
    __builtin_amdgcn_global_load_lds(
        (const __attribute__((address_space(1))) unsigned int*)g,
        (__attribute__((address_space(3))) unsigned int*)l, 16, 0, 0);
}

// ---------------------------------------------------------------------------
// fp32 -> bf16 pre-conversion of X, qkv_w, out_w (RNE, matches cvt8 exactly).
// 12,648,448 elements = 6176 blocks * 256 threads * 8 elems.
// ---------------------------------------------------------------------------
__global__ __launch_bounds__(256) void cvt_kernel(
    const float* __restrict__ X, const float* __restrict__ Wq,
    const float* __restrict__ Wo,
    ushort_t* __restrict__ Xb, ushort_t* __restrict__ Wqb,
    ushort_t* __restrict__ Wob)
{
    const long i8 = ((long)blockIdx.x * 256 + threadIdx.x) * 8;
    const float* src;
    ushort_t* dst;
    long off;
    if (i8 < XE)            { src = X;  dst = Xb;  off = i8; }
    else if (i8 < XE + QWE) { src = Wq; dst = Wqb; off = i8 - XE; }
    else                    { src = Wo; dst = Wob; off = i8 - XE - QWE; }
    *(bf16x8*)(dst + off) = cvt8(src + off);
}

// ---------------------------------------------------------------------------
// GEMM: C[m,o] = sum_k A[m,k]*W[o,k], both bf16, m97 structure:
// 128x128 tile, K-step 32, global_load_lds width-16 staging.
// MODE 0: scatter epilogue -> Q/K token-major, V dim-major (Vt[bh][d][n]).
// MODE 1: fp32 row-major store to Out.
// ---------------------------------------------------------------------------
template<int MODE>
__global__ __launch_bounds__(256) void gemm_kernel(
    const ushort_t* __restrict__ A, const ushort_t* __restrict__ W,
    ushort_t* __restrict__ QKV, float* __restrict__ Out)
{
    __shared__ __align__(16) ushort_t As[128 * 32];
    __shared__ __align__(16) ushort_t Bs[128 * 32];
    const int tid  = threadIdx.x;
    const int wave = tid >> 6, lane = tid & 63;
    const int m0 = blockIdx.y * 128;
    const int n0 = blockIdx.x * 128;

    f32x4 acc[4][4] = {};

    const int s0 = tid, s1 = tid + 256;
    int ar0 = m0 + (s0 >> 2); if (ar0 > NROWS - 1) ar0 = NROWS - 1;
    int ar1 = m0 + (s1 >> 2); if (ar1 > NROWS - 1) ar1 = NROWS - 1;
    const int br0 = n0 + (s0 >> 2);
    const int br1 = n0 + (s1 >> 2);
    const int kc0 = (s0 & 3) * 8, kc1 = (s1 & 3) * 8;

    const ushort_t* ga0 = A + (long)ar0 * DIMC + kc0;
    const ushort_t* ga1 = A + (long)ar1 * DIMC + kc1;
    const ushort_t* gw0 = W + (long)br0 * DIMC + kc0;
    const ushort_t* gw1 = W + (long)br1 * DIMC + kc1;
    ushort_t* la0 = &As[s0 * 8];
    ushort_t* la1 = &As[s1 * 8];
    ushort_t* lb0 = &Bs[s0 * 8];
    ushort_t* lb1 = &Bs[s1 * 8];

    const int wm = (wave >> 1) * 64, wn = (wave & 1) * 64;
    const int fr = lane & 15, fk = (lane >> 4) * 8;

    for (int k0 = 0; k0 < DIMC; k0 += 32) {
        load_lds16(ga0 + k0, la0);
        load_lds16(ga1 + k0, la1);
        load_lds16(gw0 + k0, lb0);
        load_lds16(gw1 + k0, lb1);
        __syncthreads();

        bf16x8 af[4], bfr[4];
        #pragma unroll
        for (int mi = 0; mi < 4; ++mi)
            af[mi] = *(const bf16x8*)&As[(wm + mi * 16 + fr) * 32 + fk];
        #pragma unroll
        for (int ni = 0; ni < 4; ++ni)
            bfr[ni] = *(const bf16x8*)&Bs[(wn + ni * 16 + fr) * 32 + fk];
        #pragma unroll
        for (int mi = 0; mi < 4; ++mi)
            #pragma unroll
            for (int ni = 0; ni < 4; ++ni)
                acc[mi][ni] = __builtin_amdgcn_mfma_f32_16x16x32_bf16(
                    af[mi], bfr[ni], acc[mi][ni], 0, 0, 0);
        __syncthreads();
    }

    const int col = lane & 15, rb = (lane >> 4) * 4;
    #pragma unroll
    for (int mi = 0; mi < 4; ++mi) {
        #pragma unroll
        for (int ni = 0; ni < 4; ++ni) {
            const int o = n0 + wn + ni * 16 + col;
            #pragma unroll
            for (int reg = 0; reg < 4; ++reg) {
                const int m = m0 + wm + mi * 16 + rb + reg;
                if (m < NROWS) {
                    const float v = acc[mi][ni][reg];
                    if (MODE == 0) {
                        const int part = o >> 10, rem = o & 1023;
                        const int h = rem >> 6, d = rem & 63;
                        const int b = m / NTOK, n = m - b * NTOK;
                        const int bh = b * 16 + h;
                        long dst;
                        if (part == 2) dst = 2L * QKV_ELEMS + ((long)bh * 64 + d) * NTOK + n;
                        else dst = (long)part * QKV_ELEMS + ((long)bh * NTOK + n) * 64 + d;
                        QKV[dst] = f2bf(v);
                    } else {
                        Out[(long)m * DIMC + o] = v;
                    }
                }
            }
        }
    }
}

// ---------------------------------------------------------------------------
// RMSNorm + RoPE in-place on bf16 Q / K (token-major). Unchanged.
// ---------------------------------------------------------------------------
__global__ __launch_bounds__(256) void rope_kernel(
    ushort_t* __restrict__ Qb, ushort_t* __restrict__ Kb,
    const float* __restrict__ cosb, const float* __restrict__ sinb,
    const float* __restrict__ wq, const float* __restrict__ wk)
{
    const int wave = threadIdx.x >> 6, lane = threadIdx.x & 63;
    const int t = blockIdx.x * 4 + wave;
    const int tensor = (t >= 132096) ? 1 : 0;
    const int r = t - tensor * 132096;
    const int n = r % NTOK;
    ushort_t* base = (tensor ? Kb : Qb) + (long)r * 64;

    const float x = bf2f(base[lane]);
    float ss = x * x;
    #pragma unroll
    for (int off = 32; off; off >>= 1) ss += __shfl_xor(ss, off);
    const float rms = rsqrtf(ss * (1.0f / 64.0f) + 1e-6f);
    const float w = (tensor ? wk : wq)[lane];
    const float xn = x * rms * w;
    const float partner = __shfl_xor(xn, 32);
    const float rot = (lane < 32) ? -partner : partner;
    const float c = cosb[n * 64 + lane];
    const float s = sinb[n * 64 + lane];
    base[lane] = f2bf(xn * c + rot * s);
}

// ---------------------------------------------------------------------------
// Patch attention (unchanged from round 5).
// ---------------------------------------------------------------------------
__global__ __launch_bounds__(256) void attn_patch_kernel(
    const ushort_t* __restrict__ Qb, const ushort_t* __restrict__ Kb,
    const ushort_t* __restrict__ Vt, ushort_t* __restrict__ AO)
{
    __shared__ __align__(16) ushort_t Q_s[32 * 72];
    __shared__ __align__(16) ushort_t KV_s[256 * 72];
    __shared__ __align__(16) ushort_t P_s[32 * 280];
    __shared__ float l_s[32];

    const int tid = threadIdx.x;
    const int wave = tid >> 6, lane = tid & 63;
    const int m_ = lane & 15, quad = lane >> 4;
    const int bh = blockIdx.x >> 5, qr = blockIdx.x & 31;
    const int b = bh >> 4, h = bh & 15;

    int r0 = qr - 3; if (r0 < 0) r0 = 0;
    int r1 = qr + 3; if (r1 > 31) r1 = 31;
    const int nrows = r1 - r0 + 1;
    const int limit = 8 + nrows * 32;

    const ushort_t* Qg  = Qb + ((long)bh * NTOK + 8 + qr * 32) * 64;
    const ushort_t* Kg  = Kb + (long)bh * NTOK * 64;
    const ushort_t* Vtg = Vt + (long)bh * 64 * NTOK;

    if (tid < 32) l_s[tid] = 0.f;
    {
        const int row = tid >> 3, c8 = (tid & 7) * 8;
        *(bf16x8*)&Q_s[row * 72 + c8] = *(const bf16x8*)(Qg + row * 64 + c8);
    }
    for (int c = tid; c < limit * 8; c += 256) {
        const int slot = c >> 3, c8 = (c & 7) * 8;
        const int tok = slot + (slot >= 8 ? r0 * 32 : 0);
        *(bf16x8*)&KV_s[slot * 72 + c8] = *(const bf16x8*)(Kg + (long)tok * 64 + c8);
    }
    __syncthreads();

    const int nb = wave * 64;
    {
        bf16x8 af[2][2], bfr[4][2];
        #pragma unroll
        for (int mt = 0; mt < 2; ++mt)
            #pragma unroll
            for (int ks = 0; ks < 2; ++ks)
                af[mt][ks] = *(const bf16x8*)&Q_s[(mt * 16 + m_) * 72 + ks * 32 + quad * 8];
        #pragma unroll
        for (int nt = 0; nt < 4; ++nt)
            #pragma unroll
            for (int ks = 0; ks < 2; ++ks)
                bfr[nt][ks] = *(const bf16x8*)&KV_s[(nb + nt * 16 + m_) * 72 + ks * 32 + quad * 8];

        f32x4 sacc[2][4] = {};
        #pragma unroll
        for (int mt = 0; mt < 2; ++mt)
            #pragma unroll
            for (int nt = 0; nt < 4; ++nt) {
                sacc[mt][nt] = __builtin_amdgcn_mfma_f32_16x16x32_bf16(
                    af[mt][0], bfr[nt][0], sacc[mt][nt], 0, 0, 0);
                sacc[mt][nt] = __builtin_amdgcn_mfma_f32_16x16x32_bf16(
                    af[mt][1], bfr[nt][1], sacc[mt][nt], 0, 0, 0);
            }

        #pragma unroll
        for (int mt = 0; mt < 2; ++mt)
            #pragma unroll
            for (int nt = 0; nt < 4; ++nt) {
                const int slot = nb + nt * 16 + m_;
                const int kc = (slot - 8) & 31;
                #pragma unroll
                for (int reg = 0; reg < 4; ++reg) {
                    const int qm = mt * 16 + quad * 4 + reg;
                    const bool val = (slot < 8) ||
                        ((slot < limit) && ((unsigned)(kc - qm + 3) <= 6u));
                    const float s = sacc[mt][nt][reg];
                    const float p = val ? __expf(s * 0.125f) : 0.f;
                    P_s[qm * 280 + slot] = f2bf(p);
                    float rs = p;
                    #pragma unroll
                    for (int off = 1; off < 16; off <<= 1) rs += __shfl_xor(rs, off);
                    if (m_ == 0) atomicAdd(&l_s[qm], rs);
                }
            }
    }
    __syncthreads();

    for (int c = tid; c < 2048; c += 256) {
        const int d = c >> 5, j = c & 31, slot0 = j * 8;
        bf16x8 v;
        if (slot0 >= limit) {
            #pragma unroll
            for (int e = 0; e < 8; ++e) v[e] = (__bf16)0.f;
        } else {
            const int tok0 = (j == 0) ? 0 : 8 + r0 * 32 + (slot0 - 8);
            v = *(const bf16x8*)(Vtg + (long)d * NTOK + tok0);
        }
        *(bf16x8*)&KV_s[d * 280 + slot0] = v;
    }
    __syncthreads();

    {
        const int d0 = wave * 16;
        f32x4 oacc[2] = {};
        #pragma unroll
        for (int ks = 0; ks < 8; ++ks) {
            const bf16x8 bv = *(const bf16x8*)&KV_s[(d0 + m_) * 280 + ks * 32 + quad * 8];
            #pragma unroll
            for (int mt = 0; mt < 2; ++mt) {
                const bf16x8 ap = *(const bf16x8*)&P_s[(mt * 16 + m_) * 280 + ks * 32 + quad * 8];
                oacc[mt] = __builtin_amdgcn_mfma_f32_16x16x32_bf16(ap, bv, oacc[mt], 0, 0, 0);
            }
        }
        #pragma unroll
        for (int mt = 0; mt < 2; ++mt)
            #pragma unroll
            for (int reg = 0; reg < 4; ++reg) {
                const int qm = mt * 16 + quad * 4 + reg;
                const int tok = 8 + qr * 32 + qm;
                const float rl = l_s[qm];
                AO[((long)(b * NTOK + tok)) * DIMC + h * 64 + d0 + m_] =
                    f2bf(oacc[mt][reg] / rl);
            }
    }
}

// ---------------------------------------------------------------------------
// Special-token attention (unchanged from round 5).
// ---------------------------------------------------------------------------
__global__ __launch_bounds__(256) void attn_special_kernel(
    const ushort_t* __restrict__ Qb, const ushort_t* __restrict__ Kb,
    const ushort_t* __restrict__ Vt, ushort_t* __restrict__ AO)
{
    __shared__ __align__(16) ushort_t Q_s[16 * 72];
    __shared__ __align__(16) ushort_t KV_s[256 * 72];
    __shared__ __align__(16) ushort_t P_s[16 * 280];
    __shared__ float l_s[16];

    const int tid = threadIdx.x;
    const int wave = tid >> 6, lane = tid & 63;
    const int m_ = lane & 15, quad = lane >> 4;
    const int bh = blockIdx.x;
    const int b = bh >> 4, h = bh & 15;

    const ushort_t* Kg  = Kb + (long)bh * NTOK * 64;
    const ushort_t* Vtg = Vt + (long)bh * 64 * NTOK;

    if (tid < 16) l_s[tid] = 0.f;
    if (tid < 128) {
        const int row = tid >> 3, c8 = (tid & 7) * 8;
        bf16x8 v;
        if (row < 8) {
            v = *(const bf16x8*)(Qb + ((long)bh * NTOK + row) * 64 + c8);
        } else {
            #pragma unroll
            for (int e = 0; e < 8; ++e) v[e] = (__bf16)0.f;
        }
        *(bf16x8*)&Q_s[row * 72 + c8] = v;
    }

    const int d0 = wave * 16;
    const int nb = wave * 64;
    f32x4 oacc = {};

    for (int ch = 0; ch < 5; ++ch) {
        const int tok0 = ch * 256;
        const int limit = (NTOK - tok0 < 256) ? (NTOK - tok0) : 256;
        __syncthreads();
        for (int c = tid; c < limit * 8; c += 256) {
            const int slot = c >> 3, c8 = (c & 7) * 8;
            *(bf16x8*)&KV_s[slot * 72 + c8] =
                *(const bf16x8*)(Kg + (long)(tok0 + slot) * 64 + c8);
        }
        __syncthreads();

        {
            bf16x8 af[2], bfr[4][2];
            #pragma unroll
            for (int ks = 0; ks < 2; ++ks)
                af[ks] = *(const bf16x8*)&Q_s[m_ * 72 + ks * 32 + quad * 8];
            #pragma unroll
            for (int nt = 0; nt < 4; ++nt)
                #pragma unroll
                for (int ks = 0; ks < 2; ++ks)
                    bfr[nt][ks] = *(const bf16x8*)&KV_s[(nb + nt * 16 + m_) * 72 + ks * 32 + quad * 8];
            f32x4 sacc[4] = {};
            #pragma unroll
            for (int nt = 0; nt < 4; ++nt) {
                sacc[nt] = __builtin_amdgcn_mfma_f32_16x16x32_bf16(af[0], bfr[nt][0], sacc[nt], 0, 0, 0);
                sacc[nt] = __builtin_amdgcn_mfma_f32_16x16x32_bf16(af[1], bfr[nt][1], sacc[nt], 0, 0, 0);
            }
            #pragma unroll
            for (int nt = 0; nt < 4; ++nt) {
                const int slot = nb + nt * 16 + m_;
                const bool val = (slot < limit);
                #pragma unroll
                for (int reg = 0; reg < 4; ++reg) {
                    const int qm = quad * 4 + reg;
                    const float p = val ? __expf(sacc[nt][reg] * 0.125f) : 0.f;
                    P_s[qm * 280 + slot] = f2bf(p);
                    float rs = p;
                    #pragma unroll
                    for (int off = 1; off < 16; off <<= 1) rs += __shfl_xor(rs, off);
                    if (m_ == 0 && qm < 8) atomicAdd(&l_s[qm], rs);
                }
            }
        }
        __syncthreads();

        for (int c = tid; c < 2048; c += 256) {
            const int d = c >> 5, j = c & 31, slot0 = j * 8;
            bf16x8 v;
            if (slot0 >= limit) {
                #pragma unroll
                for (int e = 0; e < 8; ++e) v[e] = (__bf16)0.f;
            } else {
                v = *(const bf16x8*)(Vtg + (long)d * NTOK + tok0 + slot0);
            }
            *(bf16x8*)&KV_s[d * 280 + slot0] = v;
        }
        __syncthreads();

        #pragma unroll
        for (int ks = 0; ks < 8; ++ks) {
            const bf16x8 bv = *(const bf16x8*)&KV_s[(d0 + m_) * 280 + ks * 32 + quad * 8];
            const bf16x8 ap = *(const bf16x8*)&P_s[m_ * 280 + ks * 32 + quad * 8];
            oacc = __builtin_amdgcn_mfma_f32_16x16x32_bf16(ap, bv, oacc, 0, 0, 0);
        }
    }
    __syncthreads();

    #pragma unroll
    for (int reg = 0; reg < 4; ++reg) {
        const int qm = quad * 4 + reg;
        if (qm < 8) {
            AO[((long)(b * NTOK + qm)) * DIMC + h * 64 + d0 + m_] =
                f2bf(oacc[reg] / l_s[qm]);
        }
    }
}

extern "C" void kernel_launch(void* const* d_in, const int* in_sizes, int n_in,
                              void* d_out, int out_size, void* d_ws, size_t ws_size,
                              hipStream_t stream) {
    const float* X    = (const float*)d_in[0];
    const float* fc   = (const float*)d_in[1];
    const float* fs   = (const float*)d_in[2];
    const float* qkvw = (const float*)d_in[3];
    const float* outw = (const float*)d_in[4];
    const float* nqw  = (const float*)d_in[5];
    const float* nkw  = (const float*)d_in[6];

    ushort_t* Qb  = (ushort_t*)d_ws;     // 16.9 MB each
    ushort_t* Kb  = Qb + QKV_ELEMS;
    ushort_t* Vt  = Kb + QKV_ELEMS;      // dim-major [bh][d][n]
    ushort_t* AO  = Vt + QKV_ELEMS;
    ushort_t* Xb  = AO + QKV_ELEMS;      // bf16 X (16.9 MB)
    ushort_t* Wqb = Xb + XE;             // bf16 qkv_w (6.3 MB)
    ushort_t* Wob = Wqb + QWE;           // bf16 out_w (2.1 MB)  -> total ~93 MB
    float* Out = (float*)d_out;

    // 0) fp32 -> bf16 conversion of X and weights
    cvt_kernel<<<6176, 256, 0, stream>>>(X, qkvw, outw, Xb, Wqb, Wob);
    // 1) QKV projection (all-bf16 m97-structure GEMM) + scatter
    gemm_kernel<0><<<dim3(24, 65), 256, 0, stream>>>(Xb, Wqb, Qb, nullptr);
    // 2) RMSNorm + RoPE in-place on Q,K
    rope_kernel<<<66048, 256, 0, stream>>>(Qb, Kb, fc, fs, nqw, nkw);
    // 3) masked attention -> AO
    attn_patch_kernel<<<4096, 256, 0, stream>>>(Qb, Kb, Vt, AO);
    attn_special_kernel<<<128, 256, 0, stream>>>(Qb, Kb, Vt, AO);
    // 4) output projection -> fp32 d_out
    gemm_kernel<1><<<dim3(8, 65), 256, 0, stream>>>(AO, Wob, nullptr, Out);
}

// Round 7
// 370.539 us; speedup vs baseline: 2.7167x; 1.1152x over previous
//
#include <hip/hip_runtime.h>
#include <hip/hip_bf16.h>

typedef unsigned short ushort_t;
typedef __bf16 bf16x8 __attribute__((ext_vector_type(8)));
typedef float f32x4 __attribute__((ext_vector_type(4)));

#define NTOK 1032
#define NROWS 8256       // B*N = 8*1032
#define DIMC 1024
#define QKV_ELEMS 8454144  // 8*16*1032*64 elements per tensor
#define XE 8454144         // X elements (8256*1024)
#define QWE 3145728        // qkv_w elements (3072*1024)
#define OWE 1048576        // out_w elements (1024*1024)

__device__ __forceinline__ float bf2f(ushort_t u) {
    union { unsigned int i; float f; } v; v.i = ((unsigned int)u) << 16; return v.f;
}
__device__ __forceinline__ ushort_t f2bf(float f) {
    union { float f; unsigned int i; } v; v.f = f;
    unsigned int r = v.i + 0x7fffu + ((v.i >> 16) & 1u);
    return (ushort_t)(r >> 16);
}
__device__ __forceinline__ bf16x8 cvt8(const float* p) {
    const float4 a = *(const float4*)p;
    const float4 b = *(const float4*)(p + 4);
    bf16x8 r;
    r[0] = (__bf16)a.x; r[1] = (__bf16)a.y; r[2] = (__bf16)a.z; r[3] = (__bf16)a.w;
    r[4] = (__bf16)b.x; r[5] = (__bf16)b.y; r[6] = (__bf16)b.z; r[7] = (__bf16)b.w;
    return r;
}
__device__ __forceinline__ void load_lds16(const ushort_t* g, ushort_t* l) {
    __builtin_amdgcn_global_load_lds(
        (const __attribute__((address_space(1))) unsigned int*)g,
        (__attribute__((address_space(3))) unsigned int*)l, 16, 0, 0);
}

// ---------------------------------------------------------------------------
// fp32 -> bf16 pre-conversion of X, qkv_w, out_w (RNE).
// ---------------------------------------------------------------------------
__global__ __launch_bounds__(256) void cvt_kernel(
    const float* __restrict__ X, const float* __restrict__ Wq,
    const float* __restrict__ Wo,
    ushort_t* __restrict__ Xb, ushort_t* __restrict__ Wqb,
    ushort_t* __restrict__ Wob)
{
    const long i8 = ((long)blockIdx.x * 256 + threadIdx.x) * 8;
    const float* src;
    ushort_t* dst;
    long off;
    if (i8 < XE)            { src = X;  dst = Xb;  off = i8; }
    else if (i8 < XE + QWE) { src = Wq; dst = Wqb; off = i8 - XE; }
    else                    { src = Wo; dst = Wob; off = i8 - XE - QWE; }
    *(bf16x8*)(dst + off) = cvt8(src + off);
}

// ---------------------------------------------------------------------------
// GEMM (m97 structure, unchanged from round 6).
// ---------------------------------------------------------------------------
template<int MODE>
__global__ __launch_bounds__(256) void gemm_kernel(
    const ushort_t* __restrict__ A, const ushort_t* __restrict__ W,
    ushort_t* __restrict__ QKV, float* __restrict__ Out)
{
    __shared__ __align__(16) ushort_t As[128 * 32];
    __shared__ __align__(16) ushort_t Bs[128 * 32];
    const int tid  = threadIdx.x;
    const int wave = tid >> 6, lane = tid & 63;
    const int m0 = blockIdx.y * 128;
    const int n0 = blockIdx.x * 128;

    f32x4 acc[4][4] = {};

    const int s0 = tid, s1 = tid + 256;
    int ar0 = m0 + (s0 >> 2); if (ar0 > NROWS - 1) ar0 = NROWS - 1;
    int ar1 = m0 + (s1 >> 2); if (ar1 > NROWS - 1) ar1 = NROWS - 1;
    const int br0 = n0 + (s0 >> 2);
    const int br1 = n0 + (s1 >> 2);
    const int kc0 = (s0 & 3) * 8, kc1 = (s1 & 3) * 8;

    const ushort_t* ga0 = A + (long)ar0 * DIMC + kc0;
    const ushort_t* ga1 = A + (long)ar1 * DIMC + kc1;
    const ushort_t* gw0 = W + (long)br0 * DIMC + kc0;
    const ushort_t* gw1 = W + (long)br1 * DIMC + kc1;
    ushort_t* la0 = &As[s0 * 8];
    ushort_t* la1 = &As[s1 * 8];
    ushort_t* lb0 = &Bs[s0 * 8];
    ushort_t* lb1 = &Bs[s1 * 8];

    const int wm = (wave >> 1) * 64, wn = (wave & 1) * 64;
    const int fr = lane & 15, fk = (lane >> 4) * 8;

    for (int k0 = 0; k0 < DIMC; k0 += 32) {
        load_lds16(ga0 + k0, la0);
        load_lds16(ga1 + k0, la1);
        load_lds16(gw0 + k0, lb0);
        load_lds16(gw1 + k0, lb1);
        __syncthreads();

        bf16x8 af[4], bfr[4];
        #pragma unroll
        for (int mi = 0; mi < 4; ++mi)
            af[mi] = *(const bf16x8*)&As[(wm + mi * 16 + fr) * 32 + fk];
        #pragma unroll
        for (int ni = 0; ni < 4; ++ni)
            bfr[ni] = *(const bf16x8*)&Bs[(wn + ni * 16 + fr) * 32 + fk];
        #pragma unroll
        for (int mi = 0; mi < 4; ++mi)
            #pragma unroll
            for (int ni = 0; ni < 4; ++ni)
                acc[mi][ni] = __builtin_amdgcn_mfma_f32_16x16x32_bf16(
                    af[mi], bfr[ni], acc[mi][ni], 0, 0, 0);
        __syncthreads();
    }

    const int col = lane & 15, rb = (lane >> 4) * 4;
    #pragma unroll
    for (int mi = 0; mi < 4; ++mi) {
        #pragma unroll
        for (int ni = 0; ni < 4; ++ni) {
            const int o = n0 + wn + ni * 16 + col;
            #pragma unroll
            for (int reg = 0; reg < 4; ++reg) {
                const int m = m0 + wm + mi * 16 + rb + reg;
                if (m < NROWS) {
                    const float v = acc[mi][ni][reg];
                    if (MODE == 0) {
                        const int part = o >> 10, rem = o & 1023;
                        const int h = rem >> 6, d = rem & 63;
                        const int b = m / NTOK, n = m - b * NTOK;
                        const int bh = b * 16 + h;
                        long dst;
                        if (part == 2) dst = 2L * QKV_ELEMS + ((long)bh * 64 + d) * NTOK + n;
                        else dst = (long)part * QKV_ELEMS + ((long)bh * NTOK + n) * 64 + d;
                        QKV[dst] = f2bf(v);
                    } else {
                        Out[(long)m * DIMC + o] = v;
                    }
                }
            }
        }
    }
}

// ---------------------------------------------------------------------------
// RMSNorm + RoPE in-place on bf16 Q / K (token-major). Unchanged.
// ---------------------------------------------------------------------------
__global__ __launch_bounds__(256) void rope_kernel(
    ushort_t* __restrict__ Qb, ushort_t* __restrict__ Kb,
    const float* __restrict__ cosb, const float* __restrict__ sinb,
    const float* __restrict__ wq, const float* __restrict__ wk)
{
    const int wave = threadIdx.x >> 6, lane = threadIdx.x & 63;
    const int t = blockIdx.x * 4 + wave;
    const int tensor = (t >= 132096) ? 1 : 0;
    const int r = t - tensor * 132096;
    const int n = r % NTOK;
    ushort_t* base = (tensor ? Kb : Qb) + (long)r * 64;

    const float x = bf2f(base[lane]);
    float ss = x * x;
    #pragma unroll
    for (int off = 32; off; off >>= 1) ss += __shfl_xor(ss, off);
    const float rms = rsqrtf(ss * (1.0f / 64.0f) + 1e-6f);
    const float w = (tensor ? wk : wq)[lane];
    const float xn = x * rms * w;
    const float partner = __shfl_xor(xn, 32);
    const float rot = (lane < 32) ? -partner : partner;
    const float c = cosb[n * 64 + lane];
    const float s = sinb[n * 64 + lane];
    base[lane] = f2bf(xn * c + rot * s);
}

// ---------------------------------------------------------------------------
// Patch attention v3: LDS 59.9 -> 37 KB (4 WGs/CU).
//  - Q fragments loaded DIRECT from global (A-frags are contiguous 16B).
//  - V fragments loaded DIRECT from global Vt (8-aligned slot runs are
//    contiguous tokens; slots >= limit clamp to token 0, P there is 0).
//  - P overwrites K's LDS region (K is in registers by the post-MFMA sync).
// ---------------------------------------------------------------------------
__global__ __launch_bounds__(256) void attn_patch_kernel(
    const ushort_t* __restrict__ Qb, const ushort_t* __restrict__ Kb,
    const ushort_t* __restrict__ Vt, ushort_t* __restrict__ AO)
{
    __shared__ __align__(16) ushort_t KP_s[256 * 72];  // K in S phase, P in PV phase
    __shared__ float l_s[32];

    const int tid = threadIdx.x;
    const int wave = tid >> 6, lane = tid & 63;
    const int m_ = lane & 15, quad = lane >> 4;
    const int bh = blockIdx.x >> 5, qr = blockIdx.x & 31;
    const int b = bh >> 4, h = bh & 15;

    int r0 = qr - 3; if (r0 < 0) r0 = 0;
    int r1 = qr + 3; if (r1 > 31) r1 = 31;
    const int nrows = r1 - r0 + 1;
    const int limit = 8 + nrows * 32;

    const ushort_t* Qg  = Qb + ((long)bh * NTOK + 8 + qr * 32) * 64;
    const ushort_t* Kg  = Kb + (long)bh * NTOK * 64;
    const ushort_t* Vtg = Vt + (long)bh * 64 * NTOK;

    if (tid < 32) l_s[tid] = 0.f;

    // Q fragments direct from global
    bf16x8 af[2][2];
    #pragma unroll
    for (int mt = 0; mt < 2; ++mt)
        #pragma unroll
        for (int ks = 0; ks < 2; ++ks)
            af[mt][ks] = *(const bf16x8*)(Qg + (mt * 16 + m_) * 64 + ks * 32 + quad * 8);

    // stage K -> KP_s [slot][72]
    for (int c = tid; c < limit * 8; c += 256) {
        const int slot = c >> 3, c8 = (c & 7) * 8;
        const int tok = slot + (slot >= 8 ? r0 * 32 : 0);
        *(bf16x8*)&KP_s[slot * 72 + c8] = *(const bf16x8*)(Kg + (long)tok * 64 + c8);
    }
    __syncthreads();

    // ---- S = QK^T ----
    const int nb = wave * 64;
    bf16x8 bfr[4][2];
    #pragma unroll
    for (int nt = 0; nt < 4; ++nt)
        #pragma unroll
        for (int ks = 0; ks < 2; ++ks)
            bfr[nt][ks] = *(const bf16x8*)&KP_s[(nb + nt * 16 + m_) * 72 + ks * 32 + quad * 8];

    f32x4 sacc[2][4] = {};
    #pragma unroll
    for (int mt = 0; mt < 2; ++mt)
        #pragma unroll
        for (int nt = 0; nt < 4; ++nt) {
            sacc[mt][nt] = __builtin_amdgcn_mfma_f32_16x16x32_bf16(
                af[mt][0], bfr[nt][0], sacc[mt][nt], 0, 0, 0);
            sacc[mt][nt] = __builtin_amdgcn_mfma_f32_16x16x32_bf16(
                af[mt][1], bfr[nt][1], sacc[mt][nt], 0, 0, 0);
        }
    __syncthreads();   // all K fragment reads complete -> safe to overwrite with P

    // ---- mask + exp -> P (stride 280) over K region; row sums ----
    #pragma unroll
    for (int mt = 0; mt < 2; ++mt)
        #pragma unroll
        for (int nt = 0; nt < 4; ++nt) {
            const int slot = nb + nt * 16 + m_;
            const int kc = (slot - 8) & 31;
            #pragma unroll
            for (int reg = 0; reg < 4; ++reg) {
                const int qm = mt * 16 + quad * 4 + reg;
                const bool val = (slot < 8) ||
                    ((slot < limit) && ((unsigned)(kc - qm + 3) <= 6u));
                const float s = sacc[mt][nt][reg];
                const float p = val ? __expf(s * 0.125f) : 0.f;
                KP_s[qm * 280 + slot] = f2bf(p);
                float rs = p;
                #pragma unroll
                for (int off = 1; off < 16; off <<= 1) rs += __shfl_xor(rs, off);
                if (m_ == 0) atomicAdd(&l_s[qm], rs);
            }
        }
    __syncthreads();

    // ---- O = P * V, V fragments direct from global ----
    {
        const int d0 = wave * 16;
        f32x4 oacc[2] = {};
        #pragma unroll
        for (int ks = 0; ks < 8; ++ks) {
            const int slot0 = ks * 32 + quad * 8;
            int tok0;
            if (slot0 >= limit) tok0 = 0;            // P is 0 there; V finite
            else if (slot0 < 8) tok0 = slot0;
            else tok0 = 8 + r0 * 32 + (slot0 - 8);
            const bf16x8 bv = *(const bf16x8*)(Vtg + (long)(d0 + m_) * NTOK + tok0);
            #pragma unroll
            for (int mt = 0; mt < 2; ++mt) {
                const bf16x8 ap = *(const bf16x8*)&KP_s[(mt * 16 + m_) * 280 + ks * 32 + quad * 8];
                oacc[mt] = __builtin_amdgcn_mfma_f32_16x16x32_bf16(ap, bv, oacc[mt], 0, 0, 0);
            }
        }
        #pragma unroll
        for (int mt = 0; mt < 2; ++mt)
            #pragma unroll
            for (int reg = 0; reg < 4; ++reg) {
                const int qm = mt * 16 + quad * 4 + reg;
                const int tok = 8 + qr * 32 + qm;
                const float rl = l_s[qm];
                AO[((long)(b * NTOK + tok)) * DIMC + h * 64 + wave * 16 + m_] =
                    f2bf(oacc[mt][reg] / rl);
            }
    }
}

// ---------------------------------------------------------------------------
// Special-token attention: V fragments direct from global; V-staging removed.
// ---------------------------------------------------------------------------
__global__ __launch_bounds__(256) void attn_special_kernel(
    const ushort_t* __restrict__ Qb, const ushort_t* __restrict__ Kb,
    const ushort_t* __restrict__ Vt, ushort_t* __restrict__ AO)
{
    __shared__ __align__(16) ushort_t Q_s[16 * 72];
    __shared__ __align__(16) ushort_t K_s[256 * 72];
    __shared__ __align__(16) ushort_t P_s[16 * 280];
    __shared__ float l_s[16];

    const int tid = threadIdx.x;
    const int wave = tid >> 6, lane = tid & 63;
    const int m_ = lane & 15, quad = lane >> 4;
    const int bh = blockIdx.x;
    const int b = bh >> 4, h = bh & 15;

    const ushort_t* Kg  = Kb + (long)bh * NTOK * 64;
    const ushort_t* Vtg = Vt + (long)bh * 64 * NTOK;

    if (tid < 16) l_s[tid] = 0.f;
    if (tid < 128) {
        const int row = tid >> 3, c8 = (tid & 7) * 8;
        bf16x8 v;
        if (row < 8) {
            v = *(const bf16x8*)(Qb + ((long)bh * NTOK + row) * 64 + c8);
        } else {
            #pragma unroll
            for (int e = 0; e < 8; ++e) v[e] = (__bf16)0.f;
        }
        *(bf16x8*)&Q_s[row * 72 + c8] = v;
    }

    const int d0 = wave * 16;
    const int nb = wave * 64;
    f32x4 oacc = {};

    for (int ch = 0; ch < 5; ++ch) {
        const int tok0 = ch * 256;
        const int limit = (NTOK - tok0 < 256) ? (NTOK - tok0) : 256;
        __syncthreads();   // previous PV's P reads done before restaging
        for (int c = tid; c < limit * 8; c += 256) {
            const int slot = c >> 3, c8 = (c & 7) * 8;
            *(bf16x8*)&K_s[slot * 72 + c8] =
                *(const bf16x8*)(Kg + (long)(tok0 + slot) * 64 + c8);
        }
        __syncthreads();

        // S phase
        {
            bf16x8 af[2], bfr[4][2];
            #pragma unroll
            for (int ks = 0; ks < 2; ++ks)
                af[ks] = *(const bf16x8*)&Q_s[m_ * 72 + ks * 32 + quad * 8];
            #pragma unroll
            for (int nt = 0; nt < 4; ++nt)
                #pragma unroll
                for (int ks = 0; ks < 2; ++ks)
                    bfr[nt][ks] = *(const bf16x8*)&K_s[(nb + nt * 16 + m_) * 72 + ks * 32 + quad * 8];
            f32x4 sacc[4] = {};
            #pragma unroll
            for (int nt = 0; nt < 4; ++nt) {
                sacc[nt] = __builtin_amdgcn_mfma_f32_16x16x32_bf16(af[0], bfr[nt][0], sacc[nt], 0, 0, 0);
                sacc[nt] = __builtin_amdgcn_mfma_f32_16x16x32_bf16(af[1], bfr[nt][1], sacc[nt], 0, 0, 0);
            }
            #pragma unroll
            for (int nt = 0; nt < 4; ++nt) {
                const int slot = nb + nt * 16 + m_;
                const bool val = (slot < limit);
                #pragma unroll
                for (int reg = 0; reg < 4; ++reg) {
                    const int qm = quad * 4 + reg;
                    const float p = val ? __expf(sacc[nt][reg] * 0.125f) : 0.f;
                    P_s[qm * 280 + slot] = f2bf(p);
                    float rs = p;
                    #pragma unroll
                    for (int off = 1; off < 16; off <<= 1) rs += __shfl_xor(rs, off);
                    if (m_ == 0 && qm < 8) atomicAdd(&l_s[qm], rs);
                }
            }
        }
        __syncthreads();

        // PV accumulate, V direct from global
        #pragma unroll
        for (int ks = 0; ks < 8; ++ks) {
            const int slot0 = ks * 32 + quad * 8;
            const int tok = tok0 + ((slot0 < limit) ? slot0 : 0);
            const bf16x8 bv = *(const bf16x8*)(Vtg + (long)(d0 + m_) * NTOK + tok);
            const bf16x8 ap = *(const bf16x8*)&P_s[m_ * 280 + ks * 32 + quad * 8];
            oacc = __builtin_amdgcn_mfma_f32_16x16x32_bf16(ap, bv, oacc, 0, 0, 0);
        }
    }
    __syncthreads();

    #pragma unroll
    for (int reg = 0; reg < 4; ++reg) {
        const int qm = quad * 4 + reg;
        if (qm < 8) {
            AO[((long)(b * NTOK + qm)) * DIMC + h * 64 + d0 + m_] =
                f2bf(oacc[reg] / l_s[qm]);
        }
    }
}

extern "C" void kernel_launch(void* const* d_in, const int* in_sizes, int n_in,
                              void* d_out, int out_size, void* d_ws, size_t ws_size,
                              hipStream_t stream) {
    const float* X    = (const float*)d_in[0];
    const float* fc   = (const float*)d_in[1];
    const float* fs   = (const float*)d_in[2];
    const float* qkvw = (const float*)d_in[3];
    const float* outw = (const float*)d_in[4];
    const float* nqw  = (const float*)d_in[5];
    const float* nkw  = (const float*)d_in[6];

    ushort_t* Qb  = (ushort_t*)d_ws;     // 16.9 MB each
    ushort_t* Kb  = Qb + QKV_ELEMS;
    ushort_t* Vt  = Kb + QKV_ELEMS;      // dim-major [bh][d][n]
    ushort_t* AO  = Vt + QKV_ELEMS;
    ushort_t* Xb  = AO + QKV_ELEMS;      // bf16 X (16.9 MB)
    ushort_t* Wqb = Xb + XE;             // bf16 qkv_w (6.3 MB)
    ushort_t* Wob = Wqb + QWE;           // bf16 out_w (2.1 MB)
    float* Out = (float*)d_out;

    cvt_kernel<<<6176, 256, 0, stream>>>(X, qkvw, outw, Xb, Wqb, Wob);
    gemm_kernel<0><<<dim3(24, 65), 256, 0, stream>>>(Xb, Wqb, Qb, nullptr);
    rope_kernel<<<66048, 256, 0, stream>>>(Qb, Kb, fc, fs, nqw, nkw);
    attn_patch_kernel<<<4096, 256, 0, stream>>>(Qb, Kb, Vt, AO);
    attn_special_kernel<<<128, 256, 0, stream>>>(Qb, Kb, Vt, AO);
    gemm_kernel<1><<<dim3(8, 65), 256, 0, stream>>>(AO, Wob, nullptr, Out);
}